// Round 4
// baseline (1380.750 us; speedup 1.0000x reference)
//
#include <hip/hip_runtime.h>
#include <hip/hip_bf16.h>

// GptOss grouped experts, round 4: m201-style fine-phase schedule.
// BM=256 x BN=320, BK=64, 8 waves (2M x 4N), per-wave 128x80 (FM=8, FN=5).
// 4 phases per K-tile: {ds-read subtile -> barrier -> lgkmcnt(0) ->
// setprio(1) -> 20 MFMA -> setprio(0) -> barrier}; staging (9 x
// global_load_lds w16) only in phase 3 after all reads of the buffer are
// provably complete; counted vmcnt(9) once per K-tile (T3/T4). T2 XOR
// swizzle via inverse-swizzled global source. T1 per-expert XCD swizzle.
// LDS 144 KB double-buffered. SwiGLU fused in GEMM1 epilogue.

#define TT   16384
#define DIM_ 2880
#define HID_ 2880
#define NE   8
#define TPE  2048
#define KDIM 2880
#define NT   45     // KDIM / 64

typedef __attribute__((ext_vector_type(8))) short short8;
typedef __attribute__((ext_vector_type(4))) float f32x4;

__device__ __forceinline__ unsigned short f2bf(float f) {
  unsigned u = __builtin_bit_cast(unsigned, f);
  u += 0x7fffu + ((u >> 16) & 1u);   // round-to-nearest-even
  return (unsigned short)(u >> 16);
}

__global__ void __launch_bounds__(256) cvt_f32_bf16(const float* __restrict__ src,
                                                    unsigned short* __restrict__ dst,
                                                    long n) {
  long i = ((long)blockIdx.x * 256 + threadIdx.x) * 8;
  if (i >= n) return;
  float4 a = *(const float4*)(src + i);
  float4 b = *(const float4*)(src + i + 4);
  union { unsigned short u[8]; short8 v; } r;
  r.u[0] = f2bf(a.x); r.u[1] = f2bf(a.y); r.u[2] = f2bf(a.z); r.u[3] = f2bf(a.w);
  r.u[4] = f2bf(b.x); r.u[5] = f2bf(b.y); r.u[6] = f2bf(b.z); r.u[7] = f2bf(b.w);
  *(short8*)(dst + i) = r.v;
}

// C = A(MxK) * B(NxK)^T, bf16 in, fp32 accum. BM=256, BN=320, BK=64.
// Grid: (ntm*ntn, 1, E). LDS: dbuf x (A 32KB + B 40KB) = 144 KB.
template<bool FUSE_SWIGLU>
__global__ void __launch_bounds__(512, 2) gemm4p(const unsigned short* __restrict__ A,
                                                 const unsigned short* __restrict__ B,
                                                 const float* __restrict__ bias,
                                                 void* __restrict__ Cout,
                                                 int M, int N) {
  __shared__ unsigned short As[2][256 * 64];
  __shared__ unsigned short Bs[2][320 * 64];

  const int tid  = threadIdx.x;
  const int lane = tid & 63;
  const int wid  = tid >> 6;
  const int wr   = wid >> 2;        // 0..1
  const int wc   = wid & 3;         // 0..3
  const int e    = blockIdx.z;

  // T1: per-expert bijective XCD swizzle (per_e = 144 / 72, both %8 == 0).
  const int ntn   = N / 320;
  const int ntm   = M / 256;
  const int per_e = ntn * ntm;
  const int bid   = blockIdx.x;
  const int swz   = (bid & 7) * (per_e >> 3) + (bid >> 3);
  const int m0    = (swz / ntn) * 256;
  const int n0    = (swz % ntn) * 320;

  // staging: 8 lanes per row, 16B per lane; T2 inverse-swizzle on source col
  const int srow = tid >> 3;                         // 0..63
  const int scol = ((tid & 7) ^ (srow & 7)) << 3;    // elements (chunk*8)
  const unsigned short* Aexp = A + ((size_t)e * M + m0 + srow) * KDIM + scol;
  const unsigned short* Bexp = B + ((size_t)e * N + n0 + srow) * KDIM + scol;

  auto stage = [&](int buf, int kt) {
    const unsigned short* asrc = Aexp + (size_t)kt * 64;
#pragma unroll
    for (int j = 0; j < 4; ++j)
      __builtin_amdgcn_global_load_lds(
          (const __attribute__((address_space(1))) unsigned int*)(asrc + (size_t)(j * 64) * KDIM),
          (__attribute__((address_space(3))) unsigned int*)(&As[buf][j * 4096 + tid * 8]),
          16, 0, 0);
    const unsigned short* bsrc = Bexp + (size_t)kt * 64;
#pragma unroll
    for (int j = 0; j < 5; ++j)
      __builtin_amdgcn_global_load_lds(
          (const __attribute__((address_space(1))) unsigned int*)(bsrc + (size_t)(j * 64) * KDIM),
          (__attribute__((address_space(3))) unsigned int*)(&Bs[buf][j * 4096 + tid * 8]),
          16, 0, 0);
  };

  // fragment-read addressing (swizzled), byte offsets; row stride 128 B
  const int arow = (wr * 128 + (lane & 15)) * 128;
  const int brow = (wc * 80  + (lane & 15)) * 128;
  const int swzb = (lane & 7) << 4;
  const int kb   = ((lane >> 4) & 3) * 16;
  const int c0 = kb ^ swzb;          // kk=0
  const int c1 = (64 + kb) ^ swzb;   // kk=1

  f32x4 acc[8][5] = {};

  // prologue: tiles 0,1 staged; wait tile 0 (9 of tile 1 outstanding)
  stage(0, 0);
  stage(1, 1);
  asm volatile("s_waitcnt vmcnt(9)" ::: "memory");
  __builtin_amdgcn_s_barrier();

  for (int t = 0; t < NT; ++t) {
    const int cur = t & 1;
    const char* aB = (const char*)(&As[cur][0]) + arow;
    const char* bB = (const char*)(&Bs[cur][0]) + brow;

    short8 a[4], a2[4], b0[5], b1[5];

    // ---- phase 0: read (A fm0-3, B) @ kk0; MFMA them
#pragma unroll
    for (int i = 0; i < 4; ++i) a[i] = *(const short8*)(aB + i * 2048 + c0);
#pragma unroll
    for (int f = 0; f < 5; ++f) b0[f] = *(const short8*)(bB + f * 2048 + c0);
    __builtin_amdgcn_s_barrier();
    asm volatile("s_waitcnt lgkmcnt(0)" ::: "memory");
    __builtin_amdgcn_s_setprio(1);
#pragma unroll
    for (int f = 0; f < 5; ++f)
#pragma unroll
      for (int i = 0; i < 4; ++i)
        acc[i][f] = __builtin_amdgcn_mfma_f32_16x16x32_bf16(a[i], b0[f], acc[i][f], 0, 0, 0);
    __builtin_amdgcn_s_setprio(0);
    __builtin_amdgcn_s_barrier();

    // ---- phase 1: read A fm4-7 @ kk0; MFMA them (B reused)
#pragma unroll
    for (int i = 0; i < 4; ++i) a[i] = *(const short8*)(aB + (4 + i) * 2048 + c0);
    __builtin_amdgcn_s_barrier();
    asm volatile("s_waitcnt lgkmcnt(0)" ::: "memory");
    __builtin_amdgcn_s_setprio(1);
#pragma unroll
    for (int f = 0; f < 5; ++f)
#pragma unroll
      for (int i = 0; i < 4; ++i)
        acc[4 + i][f] = __builtin_amdgcn_mfma_f32_16x16x32_bf16(a[i], b0[f], acc[4 + i][f], 0, 0, 0);
    __builtin_amdgcn_s_setprio(0);
    __builtin_amdgcn_s_barrier();

    // ---- phase 2: read ALL remaining kk1 frags (A fm0-7, B); MFMA fm0-3
#pragma unroll
    for (int i = 0; i < 4; ++i) a[i]  = *(const short8*)(aB + i * 2048 + c1);
#pragma unroll
    for (int f = 0; f < 5; ++f) b1[f] = *(const short8*)(bB + f * 2048 + c1);
#pragma unroll
    for (int i = 0; i < 4; ++i) a2[i] = *(const short8*)(aB + (4 + i) * 2048 + c1);
    __builtin_amdgcn_s_barrier();
    asm volatile("s_waitcnt lgkmcnt(0)" ::: "memory");
    __builtin_amdgcn_s_setprio(1);
#pragma unroll
    for (int f = 0; f < 5; ++f)
#pragma unroll
      for (int i = 0; i < 4; ++i)
        acc[i][f] = __builtin_amdgcn_mfma_f32_16x16x32_bf16(a[i], b1[f], acc[i][f], 0, 0, 0);
    __builtin_amdgcn_s_setprio(0);
    __builtin_amdgcn_s_barrier();
    // all waves have passed their lgkmcnt(0) on buf[cur] reads -> safe to overwrite

    // ---- phase 3: staging only (no ds_reads of cur), MFMA fm4-7 @ kk1
    const bool more = (t + 2 < NT);
    if (more) stage(cur, t + 2);
    __builtin_amdgcn_s_setprio(1);
#pragma unroll
    for (int f = 0; f < 5; ++f)
#pragma unroll
      for (int i = 0; i < 4; ++i)
        acc[4 + i][f] = __builtin_amdgcn_mfma_f32_16x16x32_bf16(a2[i], b1[f], acc[4 + i][f], 0, 0, 0);
    __builtin_amdgcn_s_setprio(0);
    if (more) asm volatile("s_waitcnt vmcnt(9)" ::: "memory");
    else      asm volatile("s_waitcnt vmcnt(0)" ::: "memory");
    __builtin_amdgcn_s_barrier();
  }

  // ---- epilogue
  const float* be = bias + (size_t)e * N;
  if constexpr (FUSE_SWIGLU) {
    unsigned short* ha = (unsigned short*)Cout + (size_t)e * M * (N >> 1);
#pragma unroll
    for (int fm = 0; fm < 8; ++fm)
#pragma unroll
      for (int fn = 0; fn < 5; ++fn) {
        const int col = n0 + wc * 80 + fn * 16 + (lane & 15);
        const float bc = be[col];
#pragma unroll
        for (int j = 0; j < 4; ++j) {
          const int row = m0 + wr * 128 + fm * 16 + (lane >> 4) * 4 + j;
          float v = acc[fm][fn][j] + bc;
          float p = __shfl_xor(v, 1);   // partner column (all lanes execute)
          if (!(lane & 1)) {
            float g  = fminf(v, 7.0f);
            float l2 = fminf(fmaxf(p, -7.0f), 7.0f);
            float act = g / (1.0f + __expf(-1.702f * g)) * (l2 + 1.0f);
            ha[(size_t)row * (N >> 1) + (col >> 1)] = f2bf(act);
          }
        }
      }
  } else {
    float* out = (float*)Cout + (size_t)e * M * N;
#pragma unroll
    for (int fm = 0; fm < 8; ++fm)
#pragma unroll
      for (int fn = 0; fn < 5; ++fn) {
        const int col = n0 + wc * 80 + fn * 16 + (lane & 15);
        const float bc = be[col];
#pragma unroll
        for (int j = 0; j < 4; ++j) {
          const int row = m0 + wr * 128 + fm * 16 + (lane >> 4) * 4 + j;
          out[(size_t)row * N + col] = acc[fm][fn][j] + bc;
        }
      }
  }
}

extern "C" void kernel_launch(void* const* d_in, const int* in_sizes, int n_in,
                              void* d_out, int out_size, void* d_ws, size_t ws_size,
                              hipStream_t stream) {
  const float* x  = (const float*)d_in[0];
  // d_in[1] = num_tokens_per_expert: fixed T/E split (reference ignores it)
  const float* w1 = (const float*)d_in[2];
  const float* b1 = (const float*)d_in[3];
  const float* w2 = (const float*)d_in[4];
  const float* b2 = (const float*)d_in[5];

  unsigned short* xb  = (unsigned short*)d_ws;
  unsigned short* w1b = xb  + (size_t)TT * DIM_;
  unsigned short* w2b = w1b + (size_t)NE * 2 * HID_ * DIM_;
  unsigned short* ha  = w2b + (size_t)NE * DIM_ * HID_;

  const long nx = (long)TT * DIM_;
  const long n1 = (long)NE * 2 * HID_ * DIM_;
  const long n2 = (long)NE * DIM_ * HID_;
  cvt_f32_bf16<<<(int)(nx / 2048), 256, 0, stream>>>(x,  xb,  nx);
  cvt_f32_bf16<<<(int)(n1 / 2048), 256, 0, stream>>>(w1, w1b, n1);
  cvt_f32_bf16<<<(int)(n2 / 2048), 256, 0, stream>>>(w2, w2b, n2);

  // GEMM1 + bias + swiglu -> ha (bf16 [E][2048][2880])
  dim3 g1((5760 / 320) * (TPE / 256), 1, NE);   // 18*8 = 144 per expert
  gemm4p<true><<<g1, 512, 0, stream>>>(xb, w1b, b1, ha, TPE, 5760);

  // GEMM2 + bias -> out (fp32 [T][2880])
  dim3 g2((DIM_ / 320) * (TPE / 256), 1, NE);   // 9*8 = 72 per expert
  gemm4p<false><<<g2, 512, 0, stream>>>(ha, w2b, b2, (float*)d_out, TPE, DIM_);
}